// Round 6
// baseline (179.336 us; speedup 1.0000x reference)
//
#include <hip/hip_runtime.h>

#define N_USER 100000
#define N_ITEM 50000
#define N_NODES 150000
#define EMB 64
#define NNZ 4000000
#define BATCH 4096
#define NSLOTS (3 * BATCH)          // 12288 output slots / compact ids
#define CAP 128                     // bucket capacity per row (λ≈26.7, P(>128)~1e-40)

// ws layout (bytes, 256-aligned):
//   BM_OFF : bitmask, 150000 bits -> 18752 B (L1-resident during scatter)
//   CUR_OFF: per-slot cursors, 12288 u32 = 49152 B          (memset 0)
//   CT_OFF : node -> slot table, 150000 i32 = 600000 B      (NOT memset: plain-
//            store race in mark resolves to a unique valid slot; unmarked
//            entries are stale junk but gated off by the bitmask)
//   BKT_OFF: buckets, 12288 x CAP x 8 B = 12.6 MB
#define BM_OFF   0
#define CUR_OFF  19200
#define CT_OFF   68352
#define BKT_OFF  668416

// K1: one thread per output slot: set node bit, publish node->slot.
__global__ void mark_kernel(const int* __restrict__ users,
                            const int* __restrict__ pos_items,
                            const int* __restrict__ neg_items,
                            unsigned int* __restrict__ bitmask,
                            int* __restrict__ ctab) {
    int t = blockIdx.x * blockDim.x + threadIdx.x;   // NSLOTS threads
    int k = t >> 12;
    int i = t & 4095;
    int node;
    if (k == 0)      node = users[i];
    else if (k == 1) node = N_USER + pos_items[i];
    else             node = N_USER + neg_items[i];
    atomicOr(bitmask + (node >> 5), 1u << (node & 31));
    ctab[node] = t;                                  // race ok: any writer's slot works
}

// K2: stream 4M edges, 4 per thread (int4/float4). Needed edges (~8%) drop an
// 8 B (col,val) record into their row's bucket. No prop atomics.
#define E4 (NNZ / 4)                 // 1,000,000
__global__ void scatter_kernel(const int4* __restrict__ rows4,
                               const int4* __restrict__ cols4,
                               const float4* __restrict__ vals4,
                               const unsigned int* __restrict__ bitmask,
                               const int* __restrict__ ctab,
                               unsigned int* __restrict__ cursor,
                               uint2* __restrict__ bucket) {
    int t = blockIdx.x * blockDim.x + threadIdx.x;
    if (t >= E4) return;
    int4   r4 = rows4[t];
    int4   c4 = cols4[t];
    float4 v4 = vals4[t];
    int    rs[4] = {r4.x, r4.y, r4.z, r4.w};
    int    cs[4] = {c4.x, c4.y, c4.z, c4.w};
    float  vs[4] = {v4.x, v4.y, v4.z, v4.w};
    #pragma unroll
    for (int u = 0; u < 4; u++) {
        int row = rs[u];
        if ((bitmask[row >> 5] >> (row & 31)) & 1) {
            int cid = ctab[row];
            unsigned int pos = atomicAdd(cursor + cid, 1u);
            if (pos < CAP)
                bucket[(size_t)cid * CAP + pos] =
                    make_uint2((unsigned int)cs[u], __float_as_uint(vs[u]));
        }
    }
}

// K3 (fused accum+gather): one wave per output slot. Re-accumulating for
// duplicate nodes (~6%) is cheaper than a prop round-trip. Per 8 entries:
// ONE load (lanes 0-7 spread over entries) + shfl broadcast, then 8
// independent 256 B embedding gathers pipelined, FMA in registers,
// one coalesced 256 B output store.
__global__ void accum_gather_kernel(const int* __restrict__ users,
                                    const int* __restrict__ pos_items,
                                    const int* __restrict__ neg_items,
                                    const float* __restrict__ user_emb,
                                    const float* __restrict__ item_emb,
                                    const int* __restrict__ ctab,
                                    const unsigned int* __restrict__ cursor,
                                    const uint2* __restrict__ bucket,
                                    float* __restrict__ out) {
    int t = blockIdx.x * blockDim.x + threadIdx.x;   // NSLOTS waves
    int slot = t >> 6;
    int lane = t & 63;
    int k = slot >> 12;
    int i = slot & 4095;
    int node;
    if (k == 0)      node = users[i];
    else if (k == 1) node = N_USER + pos_items[i];
    else             node = N_USER + neg_items[i];
    float ego = (node < N_USER)
                    ? user_emb[(size_t)node * EMB + lane]
                    : item_emb[(size_t)(node - N_USER) * EMB + lane];
    int cid = ctab[node];
    unsigned int n = cursor[cid];
    if (n > CAP) n = CAP;
    const uint2* bkt = bucket + (size_t)cid * CAP;
    float acc = 0.0f;
    for (unsigned int base = 0; base < n; base += 8) {
        unsigned int e = base + (lane & 7);
        uint2 ev = bkt[e < n ? e : n - 1];           // 1 load covers 8 entries
        #pragma unroll
        for (int u = 0; u < 8; u++) {
            if (base + (unsigned int)u < n) {        // wave-uniform guard
                int   c = __shfl((int)ev.x, u);
                float v = __int_as_float(__shfl((int)ev.y, u));
                const float* x = (c < N_USER) ? user_emb + (size_t)c * EMB
                                              : item_emb + (size_t)(c - N_USER) * EMB;
                acc += v * x[lane];                  // 64-lane 256 B gather
            }
        }
    }
    out[(size_t)slot * EMB + lane] = (ego + 3.0f * acc) * 0.25f;
}

extern "C" void kernel_launch(void* const* d_in, const int* in_sizes, int n_in,
                              void* d_out, int out_size, void* d_ws, size_t ws_size,
                              hipStream_t stream) {
    const int*   adj_rows = (const int*)  d_in[0];
    const int*   adj_cols = (const int*)  d_in[1];
    const float* adj_vals = (const float*)d_in[2];
    const float* user_emb = (const float*)d_in[3];
    const float* item_emb = (const float*)d_in[4];
    const int*   users    = (const int*)  d_in[5];
    const int*   pos      = (const int*)  d_in[6];
    const int*   neg      = (const int*)  d_in[7];
    float* out = (float*)d_out;

    unsigned int* bitmask = (unsigned int*)((char*)d_ws + BM_OFF);
    unsigned int* cursor  = (unsigned int*)((char*)d_ws + CUR_OFF);
    int*          ctab    = (int*)         ((char*)d_ws + CT_OFF);
    uint2*        bucket  = (uint2*)       ((char*)d_ws + BKT_OFF);

    // bitmask + cursors -> 0 (68 KB). ctab needs no init (see layout note).
    hipMemsetAsync((char*)d_ws + BM_OFF, 0, CT_OFF, stream);

    // NSLOTS = 12288 threads -> 48 blocks of 256
    mark_kernel<<<48, 256, 0, stream>>>(users, pos, neg, bitmask, ctab);

    // E4 = 1,000,000 threads -> 3907 blocks of 256 (guarded)
    scatter_kernel<<<3907, 256, 0, stream>>>((const int4*)adj_rows,
                                             (const int4*)adj_cols,
                                             (const float4*)adj_vals,
                                             bitmask, ctab, cursor, bucket);

    // NSLOTS waves = 786432 threads -> 3072 blocks of 256
    accum_gather_kernel<<<3072, 256, 0, stream>>>(users, pos, neg,
                                                  user_emb, item_emb,
                                                  ctab, cursor, bucket, out);
}

// Round 7
// 177.223 us; speedup vs baseline: 1.0119x; 1.0119x over previous
//
#include <hip/hip_runtime.h>

#define N_USER 100000
#define N_ITEM 50000
#define N_NODES 150000
#define EMB 64
#define NNZ 4000000
#define BATCH 4096
#define NSLOTS (3 * BATCH)          // 12288 output slots / compact ids
#define CAP 128                     // bucket capacity per row (λ≈26.7, P(>128)~1e-40)

// ws layout (bytes, 256-aligned):
//   BM_OFF : bitmask, 150000 bits -> 18752 B (L1-resident during scatter)
//   CUR_OFF: per-slot cursors, 12288 u32 = 49152 B          (memset 0)
//   CT_OFF : node -> slot table, 150000 i32 = 600000 B      (NOT memset: plain-
//            store race in mark resolves to a unique valid slot; unmarked
//            entries are stale junk but gated off by the bitmask)
//   BKT_OFF: buckets, 12288 x CAP x 8 B = 12.6 MB
#define BM_OFF   0
#define CUR_OFF  19200
#define CT_OFF   68352
#define BKT_OFF  668416

// K1: one thread per output slot: set node bit, publish node->slot.
__global__ void mark_kernel(const int* __restrict__ users,
                            const int* __restrict__ pos_items,
                            const int* __restrict__ neg_items,
                            unsigned int* __restrict__ bitmask,
                            int* __restrict__ ctab) {
    int t = blockIdx.x * blockDim.x + threadIdx.x;   // NSLOTS threads
    int k = t >> 12;
    int i = t & 4095;
    int node;
    if (k == 0)      node = users[i];
    else if (k == 1) node = N_USER + pos_items[i];
    else             node = N_USER + neg_items[i];
    atomicOr(bitmask + (node >> 5), 1u << (node & 31));
    ctab[node] = t;                                  // race ok: any writer's slot works
}

// K2: stream 4M edges, 4 per thread (int4/float4). Needed edges (~8%) drop an
// 8 B (col,val) record into their row's bucket. No prop atomics.
#define E4 (NNZ / 4)                 // 1,000,000
__global__ void scatter_kernel(const int4* __restrict__ rows4,
                               const int4* __restrict__ cols4,
                               const float4* __restrict__ vals4,
                               const unsigned int* __restrict__ bitmask,
                               const int* __restrict__ ctab,
                               unsigned int* __restrict__ cursor,
                               uint2* __restrict__ bucket) {
    int t = blockIdx.x * blockDim.x + threadIdx.x;
    if (t >= E4) return;
    int4   r4 = rows4[t];
    int4   c4 = cols4[t];
    float4 v4 = vals4[t];
    int    rs[4] = {r4.x, r4.y, r4.z, r4.w};
    int    cs[4] = {c4.x, c4.y, c4.z, c4.w};
    float  vs[4] = {v4.x, v4.y, v4.z, v4.w};
    #pragma unroll
    for (int u = 0; u < 4; u++) {
        int row = rs[u];
        if ((bitmask[row >> 5] >> (row & 31)) & 1) {
            int cid = ctab[row];
            unsigned int pos = atomicAdd(cursor + cid, 1u);
            if (pos < CAP)
                bucket[(size_t)cid * CAP + pos] =
                    make_uint2((unsigned int)cs[u], __float_as_uint(vs[u]));
        }
    }
}

// K3: one BLOCK (4 waves) per output slot. Wave w takes entry batches
// w*8, w*8+32, ... -> serial chain depth drops 4x vs one-wave-per-slot
// (R6: 44 us latency-bound, HBM 13%). Partial sums combine via 1 KB LDS;
// threads <64 add ego (loaded up-front, overlapped) and do the 256 B store.
__global__ void accum_gather_kernel(const int* __restrict__ users,
                                    const int* __restrict__ pos_items,
                                    const int* __restrict__ neg_items,
                                    const float* __restrict__ user_emb,
                                    const float* __restrict__ item_emb,
                                    const int* __restrict__ ctab,
                                    const unsigned int* __restrict__ cursor,
                                    const uint2* __restrict__ bucket,
                                    float* __restrict__ out) {
    __shared__ float lds[4][EMB];
    int slot = blockIdx.x;                           // NSLOTS blocks
    int tid  = threadIdx.x;
    int wv   = tid >> 6;
    int lane = tid & 63;
    int k = slot >> 12;
    int i = slot & 4095;
    int node;
    if (k == 0)      node = users[i];
    else if (k == 1) node = N_USER + pos_items[i];
    else             node = N_USER + neg_items[i];

    // issue ego load early (threads 0-63) so it overlaps the accumulation
    float ego = 0.0f;
    if (tid < EMB)
        ego = (node < N_USER) ? user_emb[(size_t)node * EMB + tid]
                              : item_emb[(size_t)(node - N_USER) * EMB + tid];

    int cid = ctab[node];
    unsigned int n = cursor[cid];
    if (n > CAP) n = CAP;
    const uint2* bkt = bucket + (size_t)cid * CAP;

    float acc = 0.0f;
    for (unsigned int base = (unsigned int)wv * 8; base < n; base += 32) {
        unsigned int e = base + (lane & 7);
        uint2 ev = bkt[e < n ? e : n - 1];           // 1 load covers 8 entries
        #pragma unroll
        for (int u = 0; u < 8; u++) {
            if (base + (unsigned int)u < n) {        // wave-uniform guard
                int   c = __shfl((int)ev.x, u);
                float v = __int_as_float(__shfl((int)ev.y, u));
                const float* x = (c < N_USER) ? user_emb + (size_t)c * EMB
                                              : item_emb + (size_t)(c - N_USER) * EMB;
                acc += v * x[lane];                  // 64-lane 256 B gather
            }
        }
    }
    lds[wv][lane] = acc;
    __syncthreads();
    if (tid < EMB) {
        float a = lds[0][tid] + lds[1][tid] + lds[2][tid] + lds[3][tid];
        out[(size_t)slot * EMB + tid] = (ego + 3.0f * a) * 0.25f;
    }
}

extern "C" void kernel_launch(void* const* d_in, const int* in_sizes, int n_in,
                              void* d_out, int out_size, void* d_ws, size_t ws_size,
                              hipStream_t stream) {
    const int*   adj_rows = (const int*)  d_in[0];
    const int*   adj_cols = (const int*)  d_in[1];
    const float* adj_vals = (const float*)d_in[2];
    const float* user_emb = (const float*)d_in[3];
    const float* item_emb = (const float*)d_in[4];
    const int*   users    = (const int*)  d_in[5];
    const int*   pos      = (const int*)  d_in[6];
    const int*   neg      = (const int*)  d_in[7];
    float* out = (float*)d_out;

    unsigned int* bitmask = (unsigned int*)((char*)d_ws + BM_OFF);
    unsigned int* cursor  = (unsigned int*)((char*)d_ws + CUR_OFF);
    int*          ctab    = (int*)         ((char*)d_ws + CT_OFF);
    uint2*        bucket  = (uint2*)       ((char*)d_ws + BKT_OFF);

    // bitmask + cursors -> 0 (68 KB). ctab needs no init (see layout note).
    hipMemsetAsync((char*)d_ws + BM_OFF, 0, CT_OFF, stream);

    // NSLOTS = 12288 threads -> 48 blocks of 256
    mark_kernel<<<48, 256, 0, stream>>>(users, pos, neg, bitmask, ctab);

    // E4 = 1,000,000 threads -> 3907 blocks of 256 (guarded)
    scatter_kernel<<<3907, 256, 0, stream>>>((const int4*)adj_rows,
                                             (const int4*)adj_cols,
                                             (const float4*)adj_vals,
                                             bitmask, ctab, cursor, bucket);

    // one block per slot: 12288 blocks of 256 (4 waves each)
    accum_gather_kernel<<<NSLOTS, 256, 0, stream>>>(users, pos, neg,
                                                    user_emb, item_emb,
                                                    ctab, cursor, bucket, out);
}